// Round 3
// baseline (13514.301 us; speedup 1.0000x reference)
//
#include <hip/hip_runtime.h>
#include <stdint.h>

#define B_ 32
#define T_ 256
#define DI_ 512
#define H_ 1024

using f32x4 = __attribute__((ext_vector_type(4))) float;
using s16x8 = __attribute__((ext_vector_type(8))) short;

__device__ inline unsigned short f2bf(float x) {
    unsigned u = __float_as_uint(x);
    u += 0x7FFFu + ((u >> 16) & 1u);
    return (unsigned short)(u >> 16);
}
__device__ inline float bf2f(unsigned short h) { return __uint_as_float(((unsigned)h) << 16); }
__device__ inline float sigf(float x) { return 1.f / (1.f + __expf(-x)); }
__device__ inline float tanhf_(float x) { return 1.f - 2.f / (__expf(2.f * x) + 1.f); }

// coherent (agent-scope) 16B load as 2 x 8B relaxed atomic loads: compiles to
// global_load_dwordx2 with L2-bypass bits -> always reads fresh LLC data.
__device__ inline s16x8 ld16c(const unsigned short* p) {
    union { unsigned long long u[2]; s16x8 v; } r;
    const unsigned long long* q = (const unsigned long long*)p;
    r.u[0] = __hip_atomic_load(q, __ATOMIC_RELAXED, __HIP_MEMORY_SCOPE_AGENT);
    r.u[1] = __hip_atomic_load(q + 1, __ATOMIC_RELAXED, __HIP_MEMORY_SCOPE_AGENT);
    return r.v;
}

// ---------------- conversion kernels ----------------

__global__ void conv_inputs_k(const float* __restrict__ in, unsigned short* __restrict__ out) {
    int idx = blockIdx.x * 256 + threadIdx.x;
    int d = (idx & 127) * 4;
    int row = idx >> 7;
    int t = row >> 5, b = row & 31;
    float4 v = *(const float4*)(in + ((size_t)b * T_ + t) * DI_ + d);
    unsigned long long p = (unsigned long long)f2bf(v.x)
        | ((unsigned long long)f2bf(v.y) << 16)
        | ((unsigned long long)f2bf(v.z) << 32)
        | ((unsigned long long)f2bf(v.w) << 48);
    *(unsigned long long*)(out + (size_t)row * DI_ + d) = p;
}

__global__ void conv_w_k(const float* __restrict__ src, unsigned short* __restrict__ dst,
                         int rowStride, int colOff, int K, int total4) {
    int idx = blockIdx.x * 256 + threadIdx.x;
    if (idx >= total4) return;
    int K4 = K >> 2;
    int r = idx / K4;
    int k = (idx - r * K4) << 2;
    float4 v = *(const float4*)(src + (size_t)r * rowStride + colOff + k);
    unsigned long long p = (unsigned long long)f2bf(v.x)
        | ((unsigned long long)f2bf(v.y) << 16)
        | ((unsigned long long)f2bf(v.z) << 32)
        | ((unsigned long long)f2bf(v.w) << 48);
    *(unsigned long long*)(dst + (size_t)r * K + k) = p;
}

__global__ void bias0_k(const float* __restrict__ a, const float* __restrict__ b, float* __restrict__ o) {
    int i = blockIdx.x * 256 + threadIdx.x;
    if (i < 4 * H_) o[i] = a[i] + b[i];
}

// ---------------- big parallel projection GEMM ----------------
__global__ __launch_bounds__(256) void proj_gemm_k(
    const unsigned short* __restrict__ A, const unsigned short* __restrict__ W,
    const float* __restrict__ bias, unsigned short* __restrict__ out, int K, int N) {
    __shared__ unsigned short Al[128 * 56];
    __shared__ unsigned short Bl[128 * 56];
    const int tid = threadIdx.x;
    const int lane = tid & 63, wave = tid >> 6;
    const int quad = lane >> 4, l16 = lane & 15;
    const int wm = (wave >> 1) * 64, wn = (wave & 1) * 64;
    const int bm = blockIdx.x, bn = blockIdx.y;
    const int srow = tid >> 1, shalf = tid & 1;
    const unsigned short* Ab = A + (size_t)(bm * 128 + srow) * K + shalf * 16;
    const unsigned short* Wb = W + (size_t)(bn * 128 + srow) * K + shalf * 16;

    f32x4 acc[4][4];
#pragma unroll
    for (int i = 0; i < 4; i++)
#pragma unroll
        for (int j = 0; j < 4; j++) acc[i][j] = (f32x4){0.f, 0.f, 0.f, 0.f};

    for (int kb = 0; kb < K; kb += 32) {
        s16x8 a0 = *(const s16x8*)(Ab + kb);
        s16x8 a1 = *(const s16x8*)(Ab + kb + 8);
        s16x8 b0 = *(const s16x8*)(Wb + kb);
        s16x8 b1 = *(const s16x8*)(Wb + kb + 8);
        __syncthreads();
        *(s16x8*)(&Al[srow * 56 + shalf * 16]) = a0;
        *(s16x8*)(&Al[srow * 56 + shalf * 16 + 8]) = a1;
        *(s16x8*)(&Bl[srow * 56 + shalf * 16]) = b0;
        *(s16x8*)(&Bl[srow * 56 + shalf * 16 + 8]) = b1;
        __syncthreads();
        s16x8 af[4], bf[4];
#pragma unroll
        for (int mt = 0; mt < 4; mt++) af[mt] = *(const s16x8*)(&Al[(wm + mt * 16 + l16) * 56 + quad * 8]);
#pragma unroll
        for (int nt = 0; nt < 4; nt++) bf[nt] = *(const s16x8*)(&Bl[(wn + nt * 16 + l16) * 56 + quad * 8]);
#pragma unroll
        for (int mt = 0; mt < 4; mt++)
#pragma unroll
            for (int nt = 0; nt < 4; nt++)
                acc[mt][nt] = __builtin_amdgcn_mfma_f32_16x16x32_bf16(af[mt], bf[nt], acc[mt][nt], 0, 0, 0);
    }
#pragma unroll
    for (int nt = 0; nt < 4; nt++) {
        int col = bn * 128 + wn + nt * 16 + l16;
        float bv = bias[col];
#pragma unroll
        for (int mt = 0; mt < 4; mt++) {
#pragma unroll
            for (int r = 0; r < 4; r++) {
                int rowg = bm * 128 + wm + mt * 16 + quad * 4 + r;
                out[(size_t)rowg * N + col] = f2bf(acc[mt][nt][r] + bv);
            }
        }
    }
}

// ---------------- persistent recurrence kernel ----------------
// 128 WGs x 256 threads; each WG owns 8 hidden units (ROWS = NG*8 gate rows,
// bf16 weights in LDS). Per step: MFMA gates = h_{t-1} @ W^T (all 4 waves),
// pointwise (all 256 threads = 32 batch x 8 units), then WAVE 0 ONLY stores h
// (agent-scope 8B atomics), waits vmcnt(0), publishes flag, and polls all 128
// flags (64 lanes x 8B). Other waves wait at __syncthreads -> poll traffic is
// 128 waves, not 1024.
template <int NG, bool CA, bool WROUT>
__global__ __launch_bounds__(256) void rec_k(
    const float* __restrict__ Wsrc, int wRowStride, int wColOff,
    const unsigned short* __restrict__ pre, int N,
    const unsigned short* __restrict__ clow,
    unsigned short* __restrict__ hbuf,
    unsigned short* __restrict__ cbuf,
    float* __restrict__ outh, float* __restrict__ outc,
    unsigned* __restrict__ flags) {
    constexpr int ROWS = NG * 8;            // 32 (NG=4) or 40 (NG=5)
    constexpr int NT = (ROWS + 15) / 16;    // 2 or 3
    constexpr int TOT = NT * 16;            // 32 or 48 (rows 40..47 zero-padded)
    constexpr int GLS = TOT;
    __shared__ unsigned short wl[TOT * 1032];
    __shared__ float gl[32 * GLS];
    __shared__ alignas(8) unsigned short hsh[256];
    const int tid = threadIdx.x;
    const int wg = blockIdx.x;
    const int lane = tid & 63, wave = tid >> 6;
    const int quad = lane >> 4, l16 = lane & 15;

    // stage this WG's weight rows (bf16) into LDS; pad rows zeroed
    for (int i = tid; i < TOT * 1024; i += 256) {
        int r = i >> 10, k = i & 1023;
        unsigned short v = 0;
        if (r < ROWS) {
            int g = r >> 3, u = r & 7;
            v = f2bf(Wsrc[(size_t)(g * H_ + wg * 8 + u) * wRowStride + wColOff + k]);
        }
        wl[r * 1032 + k] = v;
    }
    __syncthreads();

    const int mtile = wave & 1;
    const int n0t = wave >> 1;                       // < 2 <= NT always
    const int n1t = (wave >> 1) + 2;                 // only valid when NT==3
    const bool use2 = (NT == 3) && (n1t < NT);       // waves 0,1 take the 3rd n-tile

    const int u = tid & 7, b = tid >> 3;             // pointwise: 32 batch x 8 units
    const int unit = wg * 8 + u;
    float cst = 0.f;
    unsigned short pg[NG];
    unsigned short clw = 0;
#pragma unroll
    for (int g = 0; g < NG; g++) pg[g] = pre[(size_t)b * N + g * H_ + unit];
    if (CA) clw = clow[(size_t)b * H_ + unit];

    for (int t = 0; t < T_; ++t) {
        if (t > 0) {
            const unsigned short* hrow = hbuf + ((size_t)(t - 1) * B_ + mtile * 16 + l16) * H_ + quad * 8;
            const unsigned short* w0p = &wl[(n0t * 16 + l16) * 1032 + quad * 8];
            const unsigned short* w1p = &wl[((use2 ? n1t : n0t) * 16 + l16) * 1032 + quad * 8];
            f32x4 a0[4], a1[4];
#pragma unroll
            for (int j = 0; j < 4; j++) { a0[j] = (f32x4){0.f, 0.f, 0.f, 0.f}; a1[j] = a0[j]; }
#pragma unroll
            for (int kb = 0; kb < H_; kb += 128) {
                s16x8 h0 = ld16c(hrow + kb);
                s16x8 h1 = ld16c(hrow + kb + 32);
                s16x8 h2 = ld16c(hrow + kb + 64);
                s16x8 h3 = ld16c(hrow + kb + 96);
                a0[0] = __builtin_amdgcn_mfma_f32_16x16x32_bf16(h0, *(const s16x8*)(w0p + kb), a0[0], 0, 0, 0);
                a0[1] = __builtin_amdgcn_mfma_f32_16x16x32_bf16(h1, *(const s16x8*)(w0p + kb + 32), a0[1], 0, 0, 0);
                a0[2] = __builtin_amdgcn_mfma_f32_16x16x32_bf16(h2, *(const s16x8*)(w0p + kb + 64), a0[2], 0, 0, 0);
                a0[3] = __builtin_amdgcn_mfma_f32_16x16x32_bf16(h3, *(const s16x8*)(w0p + kb + 96), a0[3], 0, 0, 0);
                if (use2) {
                    a1[0] = __builtin_amdgcn_mfma_f32_16x16x32_bf16(h0, *(const s16x8*)(w1p + kb), a1[0], 0, 0, 0);
                    a1[1] = __builtin_amdgcn_mfma_f32_16x16x32_bf16(h1, *(const s16x8*)(w1p + kb + 32), a1[1], 0, 0, 0);
                    a1[2] = __builtin_amdgcn_mfma_f32_16x16x32_bf16(h2, *(const s16x8*)(w1p + kb + 64), a1[2], 0, 0, 0);
                    a1[3] = __builtin_amdgcn_mfma_f32_16x16x32_bf16(h3, *(const s16x8*)(w1p + kb + 96), a1[3], 0, 0, 0);
                }
            }
            f32x4 s0 = (a0[0] + a0[1]) + (a0[2] + a0[3]);
#pragma unroll
            for (int r = 0; r < 4; r++)
                gl[(mtile * 16 + quad * 4 + r) * GLS + n0t * 16 + l16] = s0[r];
            if (use2) {
                f32x4 s1 = (a1[0] + a1[1]) + (a1[2] + a1[3]);
#pragma unroll
                for (int r = 0; r < 4; r++)
                    gl[(mtile * 16 + quad * 4 + r) * GLS + n1t * 16 + l16] = s1[r];
            }
        }
        __syncthreads();
        {
            float gate[NG];
#pragma unroll
            for (int g = 0; g < NG; g++)
                gate[g] = bf2f(pg[g]) + ((t > 0) ? gl[b * GLS + g * 8 + u] : 0.f);
            float clv = CA ? bf2f(clw) : 0.f;
            if (t + 1 < T_) {  // prefetch next step's pre / c_low
#pragma unroll
                for (int g = 0; g < NG; g++) pg[g] = pre[(size_t)((t + 1) * B_ + b) * N + g * H_ + unit];
                if (CA) clw = clow[(size_t)((t + 1) * B_ + b) * H_ + unit];
            }
            float cnew, hval;
            if (CA) {
                float iv = sigf(gate[0]);
                float fp = sigf(gate[1] + 1.f);
                float fl = sigf(gate[2] + 1.f);
                float uu = tanhf_(gate[3]);
                float ov = sigf(gate[4]);
                cnew = cst * fp + clv * fl + uu * iv;
                hval = ov * tanhf_(cnew);
            } else {
                float iv = sigf(gate[0]);
                float fv = sigf(gate[1]);
                float gv = tanhf_(gate[2]);
                float ov = sigf(gate[3]);
                cnew = fv * cst + iv * gv;
                hval = ov * tanhf_(cnew);
            }
            cst = cnew;
            hsh[b * 8 + u] = f2bf(hval);
            size_t ridx = ((size_t)t * B_ + b) * H_ + unit;
            if (cbuf) cbuf[ridx] = f2bf(cnew);  // consumed only by a later dispatch
            if (WROUT) {
                outh[((size_t)b * T_ + t) * H_ + unit] = hval;
                outc[((size_t)b * T_ + t) * H_ + unit] = cnew;
            }
        }
        __syncthreads();
        if (wave == 0) {
            // publish h_t: 32 rows x 16B, lanes cover (row, 8B-half)
            int br = tid >> 1, half = tid & 1;
            unsigned long long pk = *(const unsigned long long*)(&hsh[br * 8 + half * 4]);
            unsigned long long* dst = (unsigned long long*)(hbuf + ((size_t)t * B_ + br) * H_ + wg * 8 + half * 4);
            __hip_atomic_store(dst, pk, __ATOMIC_RELAXED, __HIP_MEMORY_SCOPE_AGENT);
            asm volatile("s_waitcnt vmcnt(0)" ::: "memory");  // h visible at LLC
            if (tid == 0)
                __hip_atomic_store(&flags[wg], (unsigned)(t + 1), __ATOMIC_RELAXED, __HIP_MEMORY_SCOPE_AGENT);
            // poll all 128 flags: one 8B load per lane
            unsigned tgt = (unsigned)(t + 1);
            const unsigned long long* fq = (const unsigned long long*)flags;
            for (;;) {
                unsigned long long f = __hip_atomic_load(&fq[tid], __ATOMIC_RELAXED, __HIP_MEMORY_SCOPE_AGENT);
                unsigned lo = (unsigned)f, hi = (unsigned)(f >> 32);
                unsigned mn = lo < hi ? lo : hi;
                if (__all((int)(mn >= tgt))) break;
                __builtin_amdgcn_s_sleep(1);
            }
        }
        __syncthreads();  // release MFMA waves into step t+1
    }
}

// ---------------- launcher ----------------

extern "C" void kernel_launch(void* const* d_in, const int* in_sizes, int n_in,
                              void* d_out, int out_size, void* d_ws, size_t ws_size,
                              hipStream_t stream) {
    const float* inputs = (const float*)d_in[0];
    const float* W_ih0 = (const float*)d_in[1];
    const float* W_hh0 = (const float*)d_in[2];
    const float* b_ih0 = (const float*)d_in[3];
    const float* b_hh0 = (const float*)d_in[4];
    const float* W_ca = (const float*)d_in[5];
    const float* b_ca = (const float*)d_in[6];
    float* out = (float*)d_out;

    char* ws = (char*)d_ws;
    unsigned* flags = (unsigned*)(ws);                                       //  4 KB (4 x 128 used)
    unsigned short* A0 = (unsigned short*)(ws + 4096);                       //  8 MB
    unsigned short* Wbuf = (unsigned short*)(ws + 4096 + 8388608);           // 10.5 MB
    float* bc0 = (float*)(ws + 4096 + 8388608 + 10485760);                   // 16 KB
    unsigned short* pre = (unsigned short*)(ws + 4096 + 8388608 + 10485760 + 16384);  // 84 MB
    unsigned short* hA = pre + (size_t)8192 * 5120;
    unsigned short* hB = hA + (size_t)8192 * 1024;
    unsigned short* cA = hB + (size_t)8192 * 1024;
    unsigned short* cB = cA + (size_t)8192 * 1024;

    hipMemsetAsync(flags, 0, 4096, stream);

    // layer 0
    conv_inputs_k<<<4096, 256, 0, stream>>>(inputs, A0);
    conv_w_k<<<2048, 256, 0, stream>>>(W_ih0, Wbuf, 512, 0, 512, 4096 * 128);
    bias0_k<<<16, 256, 0, stream>>>(b_ih0, b_hh0, bc0);
    proj_gemm_k<<<dim3(64, 32), 256, 0, stream>>>(A0, Wbuf, bc0, pre, 512, 4096);
    rec_k<4, false, false><<<128, 256, 0, stream>>>(W_hh0, 1024, 0, pre, 4096, nullptr,
                                                    hA, cA, nullptr, nullptr, flags + 0);
    // layer 1
    conv_w_k<<<5120, 256, 0, stream>>>(W_ca + (size_t)0 * 5120 * 2048, Wbuf, 2048, 0, 1024, 5120 * 256);
    proj_gemm_k<<<dim3(64, 40), 256, 0, stream>>>(hA, Wbuf, b_ca + 0 * 5120, pre, 1024, 5120);
    rec_k<5, true, false><<<128, 256, 0, stream>>>(W_ca + (size_t)0 * 5120 * 2048, 2048, 1024, pre, 5120,
                                                   cA, hB, cB, nullptr, nullptr, flags + 128);
    // layer 2
    conv_w_k<<<5120, 256, 0, stream>>>(W_ca + (size_t)1 * 5120 * 2048, Wbuf, 2048, 0, 1024, 5120 * 256);
    proj_gemm_k<<<dim3(64, 40), 256, 0, stream>>>(hB, Wbuf, b_ca + 1 * 5120, pre, 1024, 5120);
    rec_k<5, true, false><<<128, 256, 0, stream>>>(W_ca + (size_t)1 * 5120 * 2048, 2048, 1024, pre, 5120,
                                                   cB, hA, cA, nullptr, nullptr, flags + 256);
    // layer 3 (writes d_out directly: hs then cs, (B,T,H) fp32)
    conv_w_k<<<5120, 256, 0, stream>>>(W_ca + (size_t)2 * 5120 * 2048, Wbuf, 2048, 0, 1024, 5120 * 256);
    proj_gemm_k<<<dim3(64, 40), 256, 0, stream>>>(hA, Wbuf, b_ca + 2 * 5120, pre, 1024, 5120);
    rec_k<5, true, true><<<128, 256, 0, stream>>>(W_ca + (size_t)2 * 5120 * 2048, 2048, 1024, pre, 5120,
                                                  cA, hB, nullptr, out, out + (size_t)8192 * 1024, flags + 384);
}

// Round 4
// 13113.550 us; speedup vs baseline: 1.0306x; 1.0306x over previous
//
#include <hip/hip_runtime.h>
#include <stdint.h>

#define B_ 32
#define T_ 256
#define DI_ 512
#define H_ 1024

using f32x4 = __attribute__((ext_vector_type(4))) float;
using s16x8 = __attribute__((ext_vector_type(8))) short;

__device__ inline unsigned short f2bf(float x) {
    unsigned u = __float_as_uint(x);
    u += 0x7FFFu + ((u >> 16) & 1u);
    return (unsigned short)(u >> 16);
}
__device__ inline float bf2f(unsigned short h) { return __uint_as_float(((unsigned)h) << 16); }
__device__ inline float sigf(float x) { return 1.f / (1.f + __expf(-x)); }
__device__ inline float tanhf_(float x) { return 1.f - 2.f / (__expf(2.f * x) + 1.f); }

// coherent (agent-scope) 16B load as 2 x 8B relaxed atomic loads -> fresh LLC data.
__device__ inline s16x8 ld16c(const unsigned short* p) {
    union { unsigned long long u[2]; s16x8 v; } r;
    const unsigned long long* q = (const unsigned long long*)p;
    r.u[0] = __hip_atomic_load(q, __ATOMIC_RELAXED, __HIP_MEMORY_SCOPE_AGENT);
    r.u[1] = __hip_atomic_load(q + 1, __ATOMIC_RELAXED, __HIP_MEMORY_SCOPE_AGENT);
    return r.v;
}

// wait until the 16 producer WGs of K-chunk c have published step >= tgt
__device__ inline void poll_chunk(const unsigned* __restrict__ flags, int c, unsigned tgt) {
    const unsigned* fp = flags + c * 16 + (threadIdx.x & 15);
    for (;;) {
        unsigned f = __hip_atomic_load(fp, __ATOMIC_RELAXED, __HIP_MEMORY_SCOPE_AGENT);
        if (__all((int)(f >= tgt))) break;
        __builtin_amdgcn_s_sleep(1);
    }
    asm volatile("" ::: "memory");  // keep dependent h loads after the poll
}

// ---------------- conversion kernels ----------------

__global__ void conv_inputs_k(const float* __restrict__ in, unsigned short* __restrict__ out) {
    int idx = blockIdx.x * 256 + threadIdx.x;
    int d = (idx & 127) * 4;
    int row = idx >> 7;
    int t = row >> 5, b = row & 31;
    float4 v = *(const float4*)(in + ((size_t)b * T_ + t) * DI_ + d);
    unsigned long long p = (unsigned long long)f2bf(v.x)
        | ((unsigned long long)f2bf(v.y) << 16)
        | ((unsigned long long)f2bf(v.z) << 32)
        | ((unsigned long long)f2bf(v.w) << 48);
    *(unsigned long long*)(out + (size_t)row * DI_ + d) = p;
}

__global__ void conv_w_k(const float* __restrict__ src, unsigned short* __restrict__ dst,
                         int rowStride, int colOff, int K, int total4) {
    int idx = blockIdx.x * 256 + threadIdx.x;
    if (idx >= total4) return;
    int K4 = K >> 2;
    int r = idx / K4;
    int k = (idx - r * K4) << 2;
    float4 v = *(const float4*)(src + (size_t)r * rowStride + colOff + k);
    unsigned long long p = (unsigned long long)f2bf(v.x)
        | ((unsigned long long)f2bf(v.y) << 16)
        | ((unsigned long long)f2bf(v.z) << 32)
        | ((unsigned long long)f2bf(v.w) << 48);
    *(unsigned long long*)(dst + (size_t)r * K + k) = p;
}

__global__ void bias0_k(const float* __restrict__ a, const float* __restrict__ b, float* __restrict__ o) {
    int i = blockIdx.x * 256 + threadIdx.x;
    if (i < 4 * H_) o[i] = a[i] + b[i];
}

// ---------------- big parallel projection GEMM ----------------
__global__ __launch_bounds__(256) void proj_gemm_k(
    const unsigned short* __restrict__ A, const unsigned short* __restrict__ W,
    const float* __restrict__ bias, unsigned short* __restrict__ out, int K, int N) {
    __shared__ unsigned short Al[128 * 56];
    __shared__ unsigned short Bl[128 * 56];
    const int tid = threadIdx.x;
    const int lane = tid & 63, wave = tid >> 6;
    const int quad = lane >> 4, l16 = lane & 15;
    const int wm = (wave >> 1) * 64, wn = (wave & 1) * 64;
    const int bm = blockIdx.x, bn = blockIdx.y;
    const int srow = tid >> 1, shalf = tid & 1;
    const unsigned short* Ab = A + (size_t)(bm * 128 + srow) * K + shalf * 16;
    const unsigned short* Wb = W + (size_t)(bn * 128 + srow) * K + shalf * 16;

    f32x4 acc[4][4];
#pragma unroll
    for (int i = 0; i < 4; i++)
#pragma unroll
        for (int j = 0; j < 4; j++) acc[i][j] = (f32x4){0.f, 0.f, 0.f, 0.f};

    for (int kb = 0; kb < K; kb += 32) {
        s16x8 a0 = *(const s16x8*)(Ab + kb);
        s16x8 a1 = *(const s16x8*)(Ab + kb + 8);
        s16x8 b0 = *(const s16x8*)(Wb + kb);
        s16x8 b1 = *(const s16x8*)(Wb + kb + 8);
        __syncthreads();
        *(s16x8*)(&Al[srow * 56 + shalf * 16]) = a0;
        *(s16x8*)(&Al[srow * 56 + shalf * 16 + 8]) = a1;
        *(s16x8*)(&Bl[srow * 56 + shalf * 16]) = b0;
        *(s16x8*)(&Bl[srow * 56 + shalf * 16 + 8]) = b1;
        __syncthreads();
        s16x8 af[4], bf[4];
#pragma unroll
        for (int mt = 0; mt < 4; mt++) af[mt] = *(const s16x8*)(&Al[(wm + mt * 16 + l16) * 56 + quad * 8]);
#pragma unroll
        for (int nt = 0; nt < 4; nt++) bf[nt] = *(const s16x8*)(&Bl[(wn + nt * 16 + l16) * 56 + quad * 8]);
#pragma unroll
        for (int mt = 0; mt < 4; mt++)
#pragma unroll
            for (int nt = 0; nt < 4; nt++)
                acc[mt][nt] = __builtin_amdgcn_mfma_f32_16x16x32_bf16(af[mt], bf[nt], acc[mt][nt], 0, 0, 0);
    }
#pragma unroll
    for (int nt = 0; nt < 4; nt++) {
        int col = bn * 128 + wn + nt * 16 + l16;
        float bv = bias[col];
#pragma unroll
        for (int mt = 0; mt < 4; mt++) {
#pragma unroll
            for (int r = 0; r < 4; r++) {
                int rowg = bm * 128 + wm + mt * 16 + quad * 4 + r;
                out[(size_t)rowg * N + col] = f2bf(acc[mt][nt][r] + bv);
            }
        }
    }
}

// ---------------- persistent recurrence kernel (producer-granular sync) ----------------
// 128 WGs x 256 threads; WG owns 8 hidden units (ROWS = NG*8 gate rows in LDS).
// No device-wide barrier: K is split into 8 chunks of 128 units; chunk c's h
// values come from producer WGs [16c,16c+16). Each wave polls only the flags of
// its next chunk (rotated start, pipelined one chunk ahead), so a slow WG never
// serializes the whole device.
template <int NG, bool CA, bool WROUT>
__global__ __launch_bounds__(256) void rec_k(
    const float* __restrict__ Wsrc, int wRowStride, int wColOff,
    const unsigned short* __restrict__ pre, int N,
    const unsigned short* __restrict__ clow,
    unsigned short* __restrict__ hbuf,
    unsigned short* __restrict__ cbuf,
    float* __restrict__ outh, float* __restrict__ outc,
    unsigned* __restrict__ flags) {
    constexpr int ROWS = NG * 8;            // 32 (NG=4) or 40 (NG=5)
    constexpr int NT = (ROWS + 15) / 16;    // 2 or 3
    constexpr int TOT = NT * 16;            // 32 or 48 (rows 40..47 zero-padded)
    constexpr int GLS = TOT;
    __shared__ unsigned short wl[TOT * 1032];
    __shared__ float gl[32 * GLS];
    __shared__ alignas(8) unsigned short hsh[256];
    const int tid = threadIdx.x;
    const int wg = blockIdx.x;
    const int lane = tid & 63, wave = tid >> 6;
    const int quad = lane >> 4, l16 = lane & 15;

    // stage this WG's weight rows (bf16) into LDS; pad rows zeroed
    for (int i = tid; i < TOT * 1024; i += 256) {
        int r = i >> 10, k = i & 1023;
        unsigned short v = 0;
        if (r < ROWS) {
            int g = r >> 3, u = r & 7;
            v = f2bf(Wsrc[(size_t)(g * H_ + wg * 8 + u) * wRowStride + wColOff + k]);
        }
        wl[r * 1032 + k] = v;
    }
    __syncthreads();

    const int mtile = wave & 1;
    const int n0t = wave >> 1;                       // < 2 <= NT always
    const int n1t = (wave >> 1) + 2;                 // only valid when NT==3
    const bool use2 = (NT == 3) && (n1t < NT);       // waves 0,1 take the 3rd n-tile
    const int cs = wg & 7;                           // rotated chunk start

    const int u = tid & 7, b = tid >> 3;             // pointwise: 32 batch x 8 units
    const int unit = wg * 8 + u;
    float cst = 0.f;
    unsigned short pg[NG];
    unsigned short clw = 0;
#pragma unroll
    for (int g = 0; g < NG; g++) pg[g] = pre[(size_t)b * N + g * H_ + unit];
    if (CA) clw = clow[(size_t)b * H_ + unit];

    for (int t = 0; t < T_; ++t) {
        if (t > 0) {
            const unsigned short* hbase = hbuf + ((size_t)(t - 1) * B_ + mtile * 16 + l16) * H_ + quad * 8;
            const unsigned short* w0p = &wl[(n0t * 16 + l16) * 1032 + quad * 8];
            const unsigned short* w1p = &wl[((use2 ? n1t : n0t) * 16 + l16) * 1032 + quad * 8];
            f32x4 a0[4], a1[4];
#pragma unroll
            for (int j = 0; j < 4; j++) { a0[j] = (f32x4){0.f, 0.f, 0.f, 0.f}; a1[j] = a0[j]; }
            // prologue: poll + load first chunk
            int c = cs;
            poll_chunk(flags, c, (unsigned)t);
            s16x8 h0 = ld16c(hbase + c * 128);
            s16x8 h1 = ld16c(hbase + c * 128 + 32);
            s16x8 h2 = ld16c(hbase + c * 128 + 64);
            s16x8 h3 = ld16c(hbase + c * 128 + 96);
#pragma unroll
            for (int i = 0; i < 8; i++) {
                s16x8 g0 = h0, g1 = h1, g2 = h2, g3 = h3;
                const int kb = c * 128;
                if (i < 7) {  // poll + prefetch next chunk while MFMA'ing this one
                    int cn = (cs + i + 1) & 7;
                    poll_chunk(flags, cn, (unsigned)t);
                    h0 = ld16c(hbase + cn * 128);
                    h1 = ld16c(hbase + cn * 128 + 32);
                    h2 = ld16c(hbase + cn * 128 + 64);
                    h3 = ld16c(hbase + cn * 128 + 96);
                    c = cn;
                }
                a0[0] = __builtin_amdgcn_mfma_f32_16x16x32_bf16(g0, *(const s16x8*)(w0p + kb), a0[0], 0, 0, 0);
                a0[1] = __builtin_amdgcn_mfma_f32_16x16x32_bf16(g1, *(const s16x8*)(w0p + kb + 32), a0[1], 0, 0, 0);
                a0[2] = __builtin_amdgcn_mfma_f32_16x16x32_bf16(g2, *(const s16x8*)(w0p + kb + 64), a0[2], 0, 0, 0);
                a0[3] = __builtin_amdgcn_mfma_f32_16x16x32_bf16(g3, *(const s16x8*)(w0p + kb + 96), a0[3], 0, 0, 0);
                if (use2) {
                    a1[0] = __builtin_amdgcn_mfma_f32_16x16x32_bf16(g0, *(const s16x8*)(w1p + kb), a1[0], 0, 0, 0);
                    a1[1] = __builtin_amdgcn_mfma_f32_16x16x32_bf16(g1, *(const s16x8*)(w1p + kb + 32), a1[1], 0, 0, 0);
                    a1[2] = __builtin_amdgcn_mfma_f32_16x16x32_bf16(g2, *(const s16x8*)(w1p + kb + 64), a1[2], 0, 0, 0);
                    a1[3] = __builtin_amdgcn_mfma_f32_16x16x32_bf16(g3, *(const s16x8*)(w1p + kb + 96), a1[3], 0, 0, 0);
                }
            }
            f32x4 s0 = (a0[0] + a0[1]) + (a0[2] + a0[3]);
#pragma unroll
            for (int r = 0; r < 4; r++)
                gl[(mtile * 16 + quad * 4 + r) * GLS + n0t * 16 + l16] = s0[r];
            if (use2) {
                f32x4 s1 = (a1[0] + a1[1]) + (a1[2] + a1[3]);
#pragma unroll
                for (int r = 0; r < 4; r++)
                    gl[(mtile * 16 + quad * 4 + r) * GLS + n1t * 16 + l16] = s1[r];
            }
        }
        __syncthreads();  // gl ready; hsh from previous step fully consumed
        {
            float gate[NG];
#pragma unroll
            for (int g = 0; g < NG; g++)
                gate[g] = bf2f(pg[g]) + ((t > 0) ? gl[b * GLS + g * 8 + u] : 0.f);
            float clv = CA ? bf2f(clw) : 0.f;
            if (t + 1 < T_) {  // prefetch next step's pre / c_low
#pragma unroll
                for (int g = 0; g < NG; g++) pg[g] = pre[(size_t)((t + 1) * B_ + b) * N + g * H_ + unit];
                if (CA) clw = clow[(size_t)((t + 1) * B_ + b) * H_ + unit];
            }
            float cnew, hval;
            if (CA) {
                float iv = sigf(gate[0]);
                float fp = sigf(gate[1] + 1.f);
                float fl = sigf(gate[2] + 1.f);
                float uu = tanhf_(gate[3]);
                float ov = sigf(gate[4]);
                cnew = cst * fp + clv * fl + uu * iv;
                hval = ov * tanhf_(cnew);
            } else {
                float iv = sigf(gate[0]);
                float fv = sigf(gate[1]);
                float gv = tanhf_(gate[2]);
                float ov = sigf(gate[3]);
                cnew = fv * cst + iv * gv;
                hval = ov * tanhf_(cnew);
            }
            cst = cnew;
            hsh[b * 8 + u] = f2bf(hval);
            size_t ridx = ((size_t)t * B_ + b) * H_ + unit;
            if (cbuf) cbuf[ridx] = f2bf(cnew);  // consumed only by a later dispatch
            if (WROUT) {
                outh[((size_t)b * T_ + t) * H_ + unit] = hval;
                outc[((size_t)b * T_ + t) * H_ + unit] = cnew;
            }
        }
        __syncthreads();  // hsh ready for wave 0's publish
        if (wave == 0) {
            // publish h_t: 32 rows x 16B, lanes cover (row, 8B-half)
            int br = tid >> 1, half = tid & 1;
            unsigned long long pk = *(const unsigned long long*)(&hsh[br * 8 + half * 4]);
            unsigned long long* dst = (unsigned long long*)(hbuf + ((size_t)t * B_ + br) * H_ + wg * 8 + half * 4);
            __hip_atomic_store(dst, pk, __ATOMIC_RELAXED, __HIP_MEMORY_SCOPE_AGENT);
            asm volatile("s_waitcnt vmcnt(0)" ::: "memory");  // h visible before flag
            if (tid == 0)
                __hip_atomic_store(&flags[wg], (unsigned)(t + 1), __ATOMIC_RELAXED, __HIP_MEMORY_SCOPE_AGENT);
        }
        // NO trailing barrier: waves 1-3 run ahead into step t+1's chunk polls;
        // hsh reuse is protected by the next step's first __syncthreads.
    }
}

// ---------------- launcher ----------------

extern "C" void kernel_launch(void* const* d_in, const int* in_sizes, int n_in,
                              void* d_out, int out_size, void* d_ws, size_t ws_size,
                              hipStream_t stream) {
    const float* inputs = (const float*)d_in[0];
    const float* W_ih0 = (const float*)d_in[1];
    const float* W_hh0 = (const float*)d_in[2];
    const float* b_ih0 = (const float*)d_in[3];
    const float* b_hh0 = (const float*)d_in[4];
    const float* W_ca = (const float*)d_in[5];
    const float* b_ca = (const float*)d_in[6];
    float* out = (float*)d_out;

    char* ws = (char*)d_ws;
    unsigned* flags = (unsigned*)(ws);                                       //  4 KB (4 x 128 used)
    unsigned short* A0 = (unsigned short*)(ws + 4096);                       //  8 MB
    unsigned short* Wbuf = (unsigned short*)(ws + 4096 + 8388608);           // 10.5 MB
    float* bc0 = (float*)(ws + 4096 + 8388608 + 10485760);                   // 16 KB
    unsigned short* pre = (unsigned short*)(ws + 4096 + 8388608 + 10485760 + 16384);  // 84 MB
    unsigned short* hA = pre + (size_t)8192 * 5120;
    unsigned short* hB = hA + (size_t)8192 * 1024;
    unsigned short* cA = hB + (size_t)8192 * 1024;
    unsigned short* cB = cA + (size_t)8192 * 1024;

    hipMemsetAsync(flags, 0, 4096, stream);

    // layer 0
    conv_inputs_k<<<4096, 256, 0, stream>>>(inputs, A0);
    conv_w_k<<<2048, 256, 0, stream>>>(W_ih0, Wbuf, 512, 0, 512, 4096 * 128);
    bias0_k<<<16, 256, 0, stream>>>(b_ih0, b_hh0, bc0);
    proj_gemm_k<<<dim3(64, 32), 256, 0, stream>>>(A0, Wbuf, bc0, pre, 512, 4096);
    rec_k<4, false, false><<<128, 256, 0, stream>>>(W_hh0, 1024, 0, pre, 4096, nullptr,
                                                    hA, cA, nullptr, nullptr, flags + 0);
    // layer 1
    conv_w_k<<<5120, 256, 0, stream>>>(W_ca + (size_t)0 * 5120 * 2048, Wbuf, 2048, 0, 1024, 5120 * 256);
    proj_gemm_k<<<dim3(64, 40), 256, 0, stream>>>(hA, Wbuf, b_ca + 0 * 5120, pre, 1024, 5120);
    rec_k<5, true, false><<<128, 256, 0, stream>>>(W_ca + (size_t)0 * 5120 * 2048, 2048, 1024, pre, 5120,
                                                   cA, hB, cB, nullptr, nullptr, flags + 128);
    // layer 2
    conv_w_k<<<5120, 256, 0, stream>>>(W_ca + (size_t)1 * 5120 * 2048, Wbuf, 2048, 0, 1024, 5120 * 256);
    proj_gemm_k<<<dim3(64, 40), 256, 0, stream>>>(hB, Wbuf, b_ca + 1 * 5120, pre, 1024, 5120);
    rec_k<5, true, false><<<128, 256, 0, stream>>>(W_ca + (size_t)1 * 5120 * 2048, 2048, 1024, pre, 5120,
                                                   cB, hA, cA, nullptr, nullptr, flags + 256);
    // layer 3 (writes d_out directly: hs then cs, (B,T,H) fp32)
    conv_w_k<<<5120, 256, 0, stream>>>(W_ca + (size_t)2 * 5120 * 2048, Wbuf, 2048, 0, 1024, 5120 * 256);
    proj_gemm_k<<<dim3(64, 40), 256, 0, stream>>>(hA, Wbuf, b_ca + 2 * 5120, pre, 1024, 5120);
    rec_k<5, true, true><<<128, 256, 0, stream>>>(W_ca + (size_t)2 * 5120 * 2048, 2048, 1024, pre, 5120,
                                                  cA, hB, nullptr, out, out + (size_t)8192 * 1024, flags + 384);
}